// Round 10
// baseline (97.632 us; speedup 1.0000x reference)
//
#include <hip/hip_runtime.h>

// B=16, N=2048, C=128, S=25, D_AGG=128, D_OUT=128
// in: A[16,2048,2048] f32, X[16,2048,128] f32, Wa[128,128] f32, ba[128] f32,
//     Wc[256,128] f32, bc[128] f32, n_samples i32
// out: [16,2048,128] f32
//
// Pipeline (R4 structure; K2 = 2-nodes-per-wave pipelined scan+gather):
//   prep   : Wa -> Wat bf16^T (64 blocks)
//   K1     : H = relu(X @ Wa + ba) -> bf16 [32768][128] (MFMA)
//   K2     : per wave: load 2 A rows (16 loads in flight), rank-scan row0,
//            issue 32 gather loads, rank-scan row1 under them, finish both.
//            Batch-affine XCD mapping. Blocks >= 4096: Wct prep.
//   K3     : out = relu([X|agg] @ Wc + bc) -> f32 + partial sumsq (MFMA)
//   K5     : out *= 1/frobnorm per batch (div_no_nan)
//
// ws: H 8MB @0, agg 8MB @8M, Wat 32K @16M, Wct 64K @16M+32K, partials @16M+128K

typedef __attribute__((ext_vector_type(8))) short short8;   // bf16x8 raw bits
typedef __attribute__((ext_vector_type(4))) float f32x4;
typedef __attribute__((ext_vector_type(4))) float fvec4;
typedef unsigned int uint;
typedef unsigned short ushort;

__device__ __forceinline__ ushort f2bf(float x) {           // RNE f32->bf16
    uint u = __builtin_bit_cast(uint, x);
    u += 0x7FFFu + ((u >> 16) & 1u);
    return (ushort)(u >> 16);
}
__device__ __forceinline__ float bflo(uint h) { uint v = h << 16;         return __builtin_bit_cast(float, v); }
__device__ __forceinline__ float bfhi(uint h) { uint v = h & 0xFFFF0000u; return __builtin_bit_cast(float, v); }

// ---------------------------------------------------------------------------
// prep: Wat[d*128+k] = bf16(Wa[k][d])  (16384 elems, 64 blocks)
// ---------------------------------------------------------------------------
__global__ __launch_bounds__(256) void prep_w_k(
    const float* __restrict__ Wa, ushort* __restrict__ Wat)
{
    int i = blockIdx.x * 256 + threadIdx.x;     // < 16384
    int d = i >> 7, k = i & 127;
    Wat[i] = f2bf(Wa[k * 128 + d]);
}

// ---------------------------------------------------------------------------
// MFMA GEMM (R4-proven): 128x128 tile, 4 waves 2x2, wave = 64x64 = 4x4 frags
// of 16x16x32. Chunk0 converted from fp32, chunk1 (K3) bf16. B pre-transposed
// [col][k]. LDS XOR swizzle on 16B granules (write AND read).
// ---------------------------------------------------------------------------
__global__ __launch_bounds__(256) void gemm_mfma_k(
    const float*  __restrict__ Xf,       // fp32 A source, chunk 0
    const ushort* __restrict__ A1,       // bf16 A source, chunk 1 (or null)
    const ushort* __restrict__ Bt,       // [128][KT] bf16
    const float*  __restrict__ bias,     // [128]
    ushort* __restrict__ outH,           // bf16 out (K1) or null
    float*  __restrict__ outF,           // f32 out (K3) or null
    float*  __restrict__ partials,       // [gridDim.x] sumsq or null
    int ktiles)
{
    __shared__ ushort Asm[128 * 128];
    __shared__ ushort Bsm[128 * 128];
    __shared__ float wred[4];
    const int tid = threadIdx.x;
    const int l = tid & 63, w = tid >> 6;
    const int wm = (w >> 1) * 64, wn = (w & 1) * 64;
    const size_t row0 = (size_t)blockIdx.x * 128;
    const int KT = ktiles << 7;

    f32x4 acc[4][4] = {};

    for (int t = 0; t < ktiles; ++t) {
        __syncthreads();
        if (t == 0) {
#pragma unroll
            for (int j = 0; j < 8; ++j) {
                int gid = (j << 8) + tid;          // 16B granule id
                int r = gid >> 4, g = gid & 15;
                const float* s = Xf + (row0 + r) * 128 + g * 8;
                short8 pk;
#pragma unroll
                for (int e = 0; e < 8; ++e) pk[e] = (short)f2bf(s[e]);
                *(short8*)&Asm[r * 128 + ((g ^ (r & 7)) << 3)] = pk;
            }
        } else {
#pragma unroll
            for (int j = 0; j < 8; ++j) {
                int gid = (j << 8) + tid;
                int r = gid >> 4, g = gid & 15;
                short8 v = *(const short8*)(A1 + (row0 + r) * 128 + g * 8);
                *(short8*)&Asm[r * 128 + ((g ^ (r & 7)) << 3)] = v;
            }
        }
#pragma unroll
        for (int j = 0; j < 8; ++j) {
            int gid = (j << 8) + tid;
            int r = gid >> 4, g = gid & 15;
            short8 v = *(const short8*)(Bt + (size_t)r * KT + (t << 7) + g * 8);
            *(short8*)&Bsm[r * 128 + ((g ^ (r & 7)) << 3)] = v;
        }
        __syncthreads();
#pragma unroll
        for (int ks = 0; ks < 4; ++ks) {
            int gg = (ks << 2) + (l >> 4);
            short8 af[4], bfr[4];
#pragma unroll
            for (int m = 0; m < 4; ++m) {
                int r = wm + m * 16 + (l & 15);
                af[m] = *(const short8*)&Asm[r * 128 + ((gg ^ (r & 7)) << 3)];
            }
#pragma unroll
            for (int n = 0; n < 4; ++n) {
                int c = wn + n * 16 + (l & 15);
                bfr[n] = *(const short8*)&Bsm[c * 128 + ((gg ^ (c & 7)) << 3)];
            }
#pragma unroll
            for (int m = 0; m < 4; ++m)
#pragma unroll
                for (int n = 0; n < 4; ++n)
                    acc[m][n] = __builtin_amdgcn_mfma_f32_16x16x32_bf16(
                        af[m], bfr[n], acc[m][n], 0, 0, 0);
        }
    }

    float bcol[4];
#pragma unroll
    for (int n = 0; n < 4; ++n) bcol[n] = bias[wn + n * 16 + (l & 15)];
    float lsum = 0.f;
#pragma unroll
    for (int m = 0; m < 4; ++m) {
        int rbase = wm + m * 16 + ((l >> 4) << 2);   // C/D: row = 4*(l>>4)+reg
#pragma unroll
        for (int n = 0; n < 4; ++n) {
            int col = wn + n * 16 + (l & 15);        // C/D: col = l&15
#pragma unroll
            for (int r = 0; r < 4; ++r) {
                float v = fmaxf(acc[m][n][r] + bcol[n], 0.f);
                size_t o = (row0 + rbase + r) * 128 + col;
                if (outH) outH[o] = f2bf(v);
                else { outF[o] = v; lsum += v * v; }
            }
        }
    }
    if (partials) {
#pragma unroll
        for (int off = 32; off > 0; off >>= 1) lsum += __shfl_down(lsum, off);
        if (l == 0) wred[w] = lsum;
        __syncthreads();
        if (tid == 0) partials[blockIdx.x] = wred[0] + wred[1] + wred[2] + wred[3];
    }
}

// ---------------------------------------------------------------------------
// rank-based ballot scan of one A row (held in v[8]): writes the first
// min(deg,S) ascending node-local indices into idx[0..], returns found.
// ---------------------------------------------------------------------------
__device__ __forceinline__ int scan_row(
    const fvec4 v[8], int S, unsigned long long lt, int l, int* idx)
{
    int base = 0;
#pragma unroll
    for (int c = 0; c < 8; ++c) {
        if (base < S) {                              // wave-uniform skip
            unsigned long long m0 = __ballot(v[c][0] != 0.f);
            unsigned long long m1 = __ballot(v[c][1] != 0.f);
            unsigned long long m2 = __ballot(v[c][2] != 0.f);
            unsigned long long m3 = __ballot(v[c][3] != 0.f);
            int below = __popcll(m0 & lt) + __popcll(m1 & lt)
                      + __popcll(m2 & lt) + __popcll(m3 & lt);
            int o0 = (int)((m0 >> l) & 1), o1 = (int)((m1 >> l) & 1);
            int o2 = (int)((m2 >> l) & 1), o3 = (int)((m3 >> l) & 1);
            int r0 = base + below;
            int r1 = r0 + o0, r2 = r1 + o1, r3 = r2 + o2;
            int e = (c << 8) + (l << 2);
            if (o0 && r0 < S) idx[r0] = e;
            if (o1 && r1 < S) idx[r1] = e + 1;
            if (o2 && r2 < S) idx[r2] = e + 2;
            if (o3 && r3 < S) idx[r3] = e + 3;
            base += __popcll(m0) + __popcll(m1) + __popcll(m2) + __popcll(m3);
        }
    }
    return base < S ? base : S;
}

// gather-max of 32 padded H rows into packed bf16 pair (i0,i1 = init)
__device__ __forceinline__ uint gather_max(
    const uint* HB, const int* idx, int l, float i0, float i1, const uint h[32])
{
    float a0[4] = {i0, i0, i0, i0}, a1[4] = {i1, i1, i1, i1};
#pragma unroll
    for (int q = 0; q < 32; ++q) {
        a0[q & 3] = fmaxf(a0[q & 3], bflo(h[q]));
        a1[q & 3] = fmaxf(a1[q & 3], bfhi(h[q]));
    }
    float r0 = fmaxf(fmaxf(a0[0], a0[1]), fmaxf(a0[2], a0[3]));
    float r1 = fmaxf(fmaxf(a1[0], a1[1]), fmaxf(a1[2], a1[3]));
    return (uint)f2bf(r0) | ((uint)f2bf(r1) << 16);
}

// ---------------------------------------------------------------------------
// K2: 2 nodes per wave, software-pipelined for MLP:
//   issue 16 A-loads (both rows) -> scan row0 -> issue 32 gather0 loads ->
//   scan row1 (VALU, overlaps gather0) -> finish row0 -> gather row1.
// Plain (cacheable) A loads: L2/L3 retention across graph replays.
// Batch-affine XCD mapping: batch = {xcd, xcd+8}; H slice stays in one L2.
// Blocks >= 4096: Wct[d*256+k] = bf16(Wc[k][d]) prep for K3.
// ---------------------------------------------------------------------------
__global__ __launch_bounds__(256) void agg_k(
    const float* __restrict__ A,        // [32768][2048]
    const uint*  __restrict__ Hu,       // [32768][64] (bf16 pairs)
    const float* __restrict__ ba,
    uint* __restrict__ aggu,            // [32768][64] (bf16 pairs)
    const int* __restrict__ nsp,
    const float* __restrict__ Wc,       // for folded prep
    ushort* __restrict__ Wct)
{
    if (blockIdx.x >= 4096) {           // folded Wct prep: 128 blocks
        int j = (blockIdx.x - 4096) * 256 + threadIdx.x;   // < 32768
        int d = j >> 8, k = j & 255;
        Wct[j] = f2bf(Wc[k * 128 + d]);
        return;
    }

    __shared__ int idxs[4][2][32];
    const int l = threadIdx.x & 63;
    const int w = threadIdx.x >> 6;
    const int bid   = blockIdx.x;
    const int xcd   = bid & 7;
    const int grp   = bid >> 3;                  // 0..511
    const int batch = ((grp >> 8) << 3) + xcd;   // {xcd, xcd+8}
    const int nb    = (batch << 11) + ((grp & 255) << 3);
    const int node0 = nb + 2 * w;
    const int node1 = node0 + 1;
    int S = nsp[0]; if (S > 32) S = 32;
    const unsigned long long lt = (1ull << l) - 1ull;
    const uint* HB = Hu + ((size_t)batch << 17); // batch*2048*64

    // issue both rows' loads: 16 x 16B in flight per wave
    fvec4 v0[8], v1[8];
    {
        const fvec4* r0 = (const fvec4*)(A + (size_t)node0 * 2048);
        const fvec4* r1 = (const fvec4*)(A + (size_t)node1 * 2048);
#pragma unroll
        for (int c = 0; c < 8; ++c) v0[c] = r0[c * 64 + l];
#pragma unroll
        for (int c = 0; c < 8; ++c) v1[c] = r1[c * 64 + l];
    }

    const float i0 = fmaxf(ba[2 * l], 0.f), i1 = fmaxf(ba[2 * l + 1], 0.f);

    // scan row0 (consumes v0; v1 stays in flight)
    int f0 = scan_row(v0, S, lt, l, idxs[w][0]);
    const bool have0 = f0 > 0;                   // wave-uniform

    // issue gather0 loads
    uint h[32];
    if (have0) {
        int fill = idxs[w][0][0];
        if (l < 32)
            idxs[w][0][l] = (l < f0) ? idxs[w][0][l] : fill;
#pragma unroll
        for (int q = 0; q < 32; ++q)
            h[q] = HB[(size_t)idxs[w][0][q] * 64 + l];
    }

    // scan row1 under gather0's latency
    int f1 = scan_row(v1, S, lt, l, idxs[w][1]);

    // finish row0
    uint pack0 = (uint)f2bf(i0) | ((uint)f2bf(i1) << 16);
    if (have0) pack0 = gather_max(HB, idxs[w][0], l, i0, i1, h);
    aggu[(size_t)node0 * 64 + l] = pack0;

    // gather row1
    uint pack1 = (uint)f2bf(i0) | ((uint)f2bf(i1) << 16);
    if (f1 > 0) {
        int fill = idxs[w][1][0];
        if (l < 32)
            idxs[w][1][l] = (l < f1) ? idxs[w][1][l] : fill;
#pragma unroll
        for (int q = 0; q < 32; ++q)
            h[q] = HB[(size_t)idxs[w][1][q] * 64 + l];
        pack1 = gather_max(HB, idxs[w][1], l, i0, i1, h);
    }
    aggu[(size_t)node1 * 64 + l] = pack1;
}

// ---------------------------------------------------------------------------
// K5: per-batch frobenius normalize in place; each block deterministically
// reduces its batch's 16 partials. div_no_nan: norm==0 -> 0.
// ---------------------------------------------------------------------------
__global__ __launch_bounds__(256) void scale_k(
    float* __restrict__ out, const float* __restrict__ partials)
{
    const int blk = blockIdx.x;
    const int b = blk >> 6;                          // 64 blocks per batch
    float s = 0.f;
#pragma unroll
    for (int i = 0; i < 16; ++i) s += partials[b * 16 + i];
    float norm = sqrtf(s);
    float sc = (norm > 0.f) ? (1.f / norm) : 0.f;
    fvec4* o4 = (fvec4*)out;
    int i0 = blk * 1024 + threadIdx.x;
#pragma unroll
    for (int k = 0; k < 4; ++k) {
        fvec4 v = o4[i0 + k * 256];
        o4[i0 + k * 256] = v * sc;
    }
}

extern "C" void kernel_launch(void* const* d_in, const int* in_sizes, int n_in,
                              void* d_out, int out_size, void* d_ws, size_t ws_size,
                              hipStream_t stream) {
    const float* A  = (const float*)d_in[0];
    const float* X  = (const float*)d_in[1];
    const float* Wa = (const float*)d_in[2];
    const float* ba = (const float*)d_in[3];
    const float* Wc = (const float*)d_in[4];
    const float* bc = (const float*)d_in[5];
    const int*  nsp = (const int*)d_in[6];

    float* out = (float*)d_out;
    char* ws = (char*)d_ws;
    ushort* H        = (ushort*)ws;                              // 8 MB
    ushort* agg      = (ushort*)(ws + (8u << 20));               // 8 MB
    ushort* Wat      = (ushort*)(ws + (16u << 20));              // 32 KB
    ushort* Wct      = (ushort*)(ws + (16u << 20) + 32768);      // 64 KB
    float*  partials = (float*) (ws + (16u << 20) + 131072);     // 1 KB

    // Wa -> bf16 transposed
    prep_w_k<<<64, 256, 0, stream>>>(Wa, Wat);
    // K1: H = relu(X @ Wa + ba), bf16
    gemm_mfma_k<<<256, 256, 0, stream>>>(X, nullptr, Wat, ba, H, nullptr, nullptr, 1);
    // K2: 2-node pipelined scan+gather (+ folded Wct prep blocks >= 4096)
    agg_k<<<4096 + 128, 256, 0, stream>>>(A, (const uint*)H, ba, (uint*)agg,
                                          nsp, Wc, Wct);
    // K3: out = relu([X|agg] @ Wc + bc) + partial sumsq
    gemm_mfma_k<<<256, 256, 0, stream>>>(X, agg, Wct, bc, nullptr, out, partials, 2);
    // K5: normalize
    scale_k<<<1024, 256, 0, stream>>>(out, partials);
}